// Round 1
// baseline (6998.026 us; speedup 1.0000x reference)
//
#include <hip/hip_runtime.h>
#include <math.h>

#define B_  2
#define T_  2048
#define D_  2048
#define H_  16
#define DH  128
#define DS  64
#define BT  (B_ * T_)          // 4096 rows
// SCALE = sqrt(DS) = 8  -> multiply scores by 0.125f

// ---------------------------------------------------------------------------
// GEMM: C = A @ W^T.  A: M x K row-major, W: N x K row-major, C: M x N.
// 64x64 block tile, K-tile 16, 256 threads, 4x4 per thread. Pure fp32.
// ---------------------------------------------------------------------------
#define GT  64
#define GKT 16

__global__ __launch_bounds__(256)
void gemm_bt(const float* __restrict__ A, const float* __restrict__ W,
             float* __restrict__ C, int M, int N, int K) {
    __shared__ float As[GKT][GT];
    __shared__ float Bs[GKT][GT];

    const int tid = threadIdx.x;
    const int bm  = blockIdx.y * GT;
    const int bn  = blockIdx.x * GT;

    const int tr = (tid >> 4) << 2;   // 0..60, row offset of 4x4 micro tile
    const int tc = (tid & 15) << 2;   // 0..60, col offset

    const int lr = tid >> 2;          // 0..63  (row loaded)
    const int lk = (tid & 3) << 2;    // 0,4,8,12 (k offset loaded, float4)

    float acc[4][4] = {{0.f,0.f,0.f,0.f},{0.f,0.f,0.f,0.f},
                       {0.f,0.f,0.f,0.f},{0.f,0.f,0.f,0.f}};

    const float* Arow = A + (size_t)(bm + lr) * K + lk;
    const float* Wrow = W + (size_t)(bn + lr) * K + lk;

    for (int k0 = 0; k0 < K; k0 += GKT) {
        float4 a4 = *(const float4*)(Arow + k0);
        float4 b4 = *(const float4*)(Wrow + k0);
        __syncthreads();               // protect previous iteration's reads
        As[lk + 0][lr] = a4.x; As[lk + 1][lr] = a4.y;
        As[lk + 2][lr] = a4.z; As[lk + 3][lr] = a4.w;
        Bs[lk + 0][lr] = b4.x; Bs[lk + 1][lr] = b4.y;
        Bs[lk + 2][lr] = b4.z; Bs[lk + 3][lr] = b4.w;
        __syncthreads();
        #pragma unroll
        for (int k = 0; k < GKT; ++k) {
            float4 av4 = *(const float4*)&As[k][tr];
            float4 bv4 = *(const float4*)&Bs[k][tc];
            float av[4] = {av4.x, av4.y, av4.z, av4.w};
            float bv[4] = {bv4.x, bv4.y, bv4.z, bv4.w};
            #pragma unroll
            for (int i = 0; i < 4; ++i)
                #pragma unroll
                for (int j = 0; j < 4; ++j)
                    acc[i][j] += av[i] * bv[j];
        }
    }

    #pragma unroll
    for (int i = 0; i < 4; ++i) {
        float4 o;
        o.x = acc[i][0]; o.y = acc[i][1]; o.z = acc[i][2]; o.w = acc[i][3];
        *(float4*)(C + (size_t)(bm + tr + i) * N + bn + tc) = o;
    }
}

// ---------------------------------------------------------------------------
// Differential attention, fused per (b, h, 32 query rows).
// Two-pass: pass 1 computes per-row (m1,l1,m2,l2); pass 2 recomputes scores,
// builds combined weights w = exp(s1-m1)/l1 - lam*exp(s2-m2)/l2, accumulates
// w * V into registers. Out may alias Q (block writes only the slice it read).
// ---------------------------------------------------------------------------
#define QB   32
#define SB   64
#define PADC 132   // padded LDS row length (breaks stride-512B bank conflicts)

__global__ __launch_bounds__(256)
void diff_attn(const float* Qbuf,
               const float* __restrict__ Kbuf,
               const float* __restrict__ Vbuf,
               const float* __restrict__ lambda_param,
               float* Out) {
    __shared__ float Qs[QB][PADC];
    __shared__ float KVs[SB][PADC];
    __shared__ float Ws[QB][SB + 1];

    const int tid = threadIdx.x;
    const int b   = blockIdx.z;
    const int h   = blockIdx.y;
    const int t0  = blockIdx.x * QB;

    const int i = tid >> 3;   // query row within tile, 0..31
    const int u = tid & 7;    // col-group / j-group id, 0..7

    const float lam = 1.f / (1.f + __expf(-lambda_param[h]));

    const size_t rs = (size_t)D_;
    const float* Qg = Qbuf + (size_t)(b * T_ + t0) * rs + h * DH;
    const float* Kg = Kbuf + (size_t)(b * T_) * rs + h * DH;
    const float* Vg = Vbuf + (size_t)(b * T_) * rs + h * DH;

    // stage Q tile (32 x 128)
    for (int idx = tid; idx < QB * DH / 4; idx += 256) {
        int r = idx >> 5, c = (idx & 31) << 2;
        *(float4*)&Qs[r][c] = *(const float4*)(Qg + (size_t)r * rs + c);
    }
    __syncthreads();

    float m1 = -1e30f, l1 = 0.f, m2 = -1e30f, l2 = 0.f;

    // ---------------- pass 1: softmax stats ----------------
    for (int s0 = 0; s0 < T_; s0 += SB) {
        __syncthreads();
        for (int idx = tid; idx < SB * DH / 4; idx += 256) {
            int r = idx >> 5, c = (idx & 31) << 2;
            *(float4*)&KVs[r][c] = *(const float4*)(Kg + (size_t)(s0 + r) * rs + c);
        }
        __syncthreads();

        float s1v[8] = {0,0,0,0,0,0,0,0};
        float s2v[8] = {0,0,0,0,0,0,0,0};
        for (int d4 = 0; d4 < 16; ++d4) {
            float4 q = *(const float4*)&Qs[i][d4 * 4];
            #pragma unroll
            for (int jj = 0; jj < 8; ++jj) {
                float4 kv = *(const float4*)&KVs[u * 8 + jj][d4 * 4];
                s1v[jj] += q.x*kv.x + q.y*kv.y + q.z*kv.z + q.w*kv.w;
            }
        }
        for (int d4 = 16; d4 < 32; ++d4) {
            float4 q = *(const float4*)&Qs[i][d4 * 4];
            #pragma unroll
            for (int jj = 0; jj < 8; ++jj) {
                float4 kv = *(const float4*)&KVs[u * 8 + jj][d4 * 4];
                s2v[jj] += q.x*kv.x + q.y*kv.y + q.z*kv.z + q.w*kv.w;
            }
        }

        float lm1 = -1e30f, lm2 = -1e30f;
        #pragma unroll
        for (int jj = 0; jj < 8; ++jj) {
            s1v[jj] *= 0.125f; s2v[jj] *= 0.125f;
            lm1 = fmaxf(lm1, s1v[jj]); lm2 = fmaxf(lm2, s2v[jj]);
        }
        #pragma unroll
        for (int mask = 1; mask < 8; mask <<= 1) {
            lm1 = fmaxf(lm1, __shfl_xor(lm1, mask));
            lm2 = fmaxf(lm2, __shfl_xor(lm2, mask));
        }
        float ls1 = 0.f, ls2 = 0.f;
        #pragma unroll
        for (int jj = 0; jj < 8; ++jj) {
            ls1 += __expf(s1v[jj] - lm1);
            ls2 += __expf(s2v[jj] - lm2);
        }
        #pragma unroll
        for (int mask = 1; mask < 8; mask <<= 1) {
            ls1 += __shfl_xor(ls1, mask);
            ls2 += __shfl_xor(ls2, mask);
        }
        // merge tile stats into running stats
        float mn1 = fmaxf(m1, lm1);
        l1 = l1 * __expf(m1 - mn1) + ls1 * __expf(lm1 - mn1);
        m1 = mn1;
        float mn2 = fmaxf(m2, lm2);
        l2 = l2 * __expf(m2 - mn2) + ls2 * __expf(lm2 - mn2);
        m2 = mn2;
    }

    const float il1 = 1.f / l1;
    const float il2 = lam / l2;

    float4 acc[4];
    #pragma unroll
    for (int c = 0; c < 4; ++c) acc[c] = make_float4(0.f, 0.f, 0.f, 0.f);

    // ---------------- pass 2: weights + PV ----------------
    for (int s0 = 0; s0 < T_; s0 += SB) {
        __syncthreads();   // previous V reads done
        for (int idx = tid; idx < SB * DH / 4; idx += 256) {
            int r = idx >> 5, c = (idx & 31) << 2;
            *(float4*)&KVs[r][c] = *(const float4*)(Kg + (size_t)(s0 + r) * rs + c);
        }
        __syncthreads();

        float s1v[8] = {0,0,0,0,0,0,0,0};
        float s2v[8] = {0,0,0,0,0,0,0,0};
        for (int d4 = 0; d4 < 16; ++d4) {
            float4 q = *(const float4*)&Qs[i][d4 * 4];
            #pragma unroll
            for (int jj = 0; jj < 8; ++jj) {
                float4 kv = *(const float4*)&KVs[u * 8 + jj][d4 * 4];
                s1v[jj] += q.x*kv.x + q.y*kv.y + q.z*kv.z + q.w*kv.w;
            }
        }
        for (int d4 = 16; d4 < 32; ++d4) {
            float4 q = *(const float4*)&Qs[i][d4 * 4];
            #pragma unroll
            for (int jj = 0; jj < 8; ++jj) {
                float4 kv = *(const float4*)&KVs[u * 8 + jj][d4 * 4];
                s2v[jj] += q.x*kv.x + q.y*kv.y + q.z*kv.z + q.w*kv.w;
            }
        }
        #pragma unroll
        for (int jj = 0; jj < 8; ++jj) {
            float w = __expf(s1v[jj] * 0.125f - m1) * il1
                    - __expf(s2v[jj] * 0.125f - m2) * il2;
            Ws[i][u * 8 + jj] = w;
        }
        __syncthreads();   // K reads + Ws writes complete

        for (int idx = tid; idx < SB * DH / 4; idx += 256) {
            int r = idx >> 5, c = (idx & 31) << 2;
            *(float4*)&KVs[r][c] = *(const float4*)(Vg + (size_t)(s0 + r) * rs + c);
        }
        __syncthreads();   // V tile ready

        for (int j = 0; j < SB; ++j) {
            float w = Ws[i][j];
            #pragma unroll
            for (int c = 0; c < 4; ++c) {
                float4 v = *(const float4*)&KVs[j][u * 16 + c * 4];
                acc[c].x += w * v.x; acc[c].y += w * v.y;
                acc[c].z += w * v.z; acc[c].w += w * v.w;
            }
        }
    }

    // write output slice (may alias Q region of this exact tile)
    float* Og = Out + (size_t)(b * T_ + t0 + i) * rs + h * DH + u * 16;
    #pragma unroll
    for (int c = 0; c < 4; ++c)
        *(float4*)(Og + c * 4) = acc[c];
}

// ---------------------------------------------------------------------------
extern "C" void kernel_launch(void* const* d_in, const int* in_sizes, int n_in,
                              void* d_out, int out_size, void* d_ws, size_t ws_size,
                              hipStream_t stream) {
    const float* x    = (const float*)d_in[0];
    const float* W_q  = (const float*)d_in[1];
    const float* W_k  = (const float*)d_in[2];
    const float* W_v  = (const float*)d_in[3];
    const float* W_o  = (const float*)d_in[4];
    const float* lamp = (const float*)d_in[5];
    float* out = (float*)d_out;

    float* Qbuf = (float*)d_ws;                      // 4096 x 2048 (32 MB)
    float* Kbuf = Qbuf + (size_t)BT * D_;            // 32 MB
    float* Vbuf = Kbuf + (size_t)BT * D_;            // 32 MB

    dim3 gg(D_ / GT, BT / GT);                       // (32, 64)
    gemm_bt<<<gg, 256, 0, stream>>>(x, W_q, Qbuf, BT, D_, D_);
    gemm_bt<<<gg, 256, 0, stream>>>(x, W_k, Kbuf, BT, D_, D_);
    gemm_bt<<<gg, 256, 0, stream>>>(x, W_v, Vbuf, BT, D_, D_);

    dim3 ga(T_ / QB, H_, B_);                        // (64, 16, 2)
    diff_attn<<<ga, 256, 0, stream>>>(Qbuf, Kbuf, Vbuf, lamp, Qbuf /*Out aliases Q*/);

    gemm_bt<<<gg, 256, 0, stream>>>(Qbuf, W_o, out, BT, D_, D_);
}

// Round 2
// 2184.096 us; speedup vs baseline: 3.2041x; 3.2041x over previous
//
#include <hip/hip_runtime.h>
#include <math.h>

#define B_  2
#define T_  2048
#define D_  2048
#define H_  16
#define DH  128
#define BT  (B_ * T_)          // 4096 rows

typedef float  f32x4 __attribute__((ext_vector_type(4)));
typedef short  s16x8 __attribute__((ext_vector_type(8)));

__device__ __forceinline__ unsigned short bf16_rne(float f) {
    union { float f; unsigned u; } c; c.f = f;
    unsigned r = c.u + 0x7fffu + ((c.u >> 16) & 1u);
    return (unsigned short)(r >> 16);
}
__device__ __forceinline__ float bf16_to_f(unsigned short h) {
    union { unsigned u; float f; } c; c.u = ((unsigned)h) << 16; return c.f;
}

// ---------------------------------------------------------------------------
// GEMM: C = A @ W^T.  A: M x K row-major, W: N x K row-major. fp32 output.
// ---------------------------------------------------------------------------
#define GT  64
#define GKT 16

__global__ __launch_bounds__(256)
void gemm_bt(const float* __restrict__ A, const float* __restrict__ W,
             float* __restrict__ C, int M, int N, int K) {
    __shared__ float As[GKT][GT];
    __shared__ float Bs[GKT][GT];

    const int tid = threadIdx.x;
    const int bm  = blockIdx.y * GT;
    const int bn  = blockIdx.x * GT;
    const int tr = (tid >> 4) << 2;
    const int tc = (tid & 15) << 2;
    const int lr = tid >> 2;
    const int lk = (tid & 3) << 2;

    float acc[4][4] = {{0.f,0.f,0.f,0.f},{0.f,0.f,0.f,0.f},
                       {0.f,0.f,0.f,0.f},{0.f,0.f,0.f,0.f}};

    const float* Arow = A + (size_t)(bm + lr) * K + lk;
    const float* Wrow = W + (size_t)(bn + lr) * K + lk;

    for (int k0 = 0; k0 < K; k0 += GKT) {
        float4 a4 = *(const float4*)(Arow + k0);
        float4 b4 = *(const float4*)(Wrow + k0);
        __syncthreads();
        As[lk + 0][lr] = a4.x; As[lk + 1][lr] = a4.y;
        As[lk + 2][lr] = a4.z; As[lk + 3][lr] = a4.w;
        Bs[lk + 0][lr] = b4.x; Bs[lk + 1][lr] = b4.y;
        Bs[lk + 2][lr] = b4.z; Bs[lk + 3][lr] = b4.w;
        __syncthreads();
        #pragma unroll
        for (int k = 0; k < GKT; ++k) {
            float4 av4 = *(const float4*)&As[k][tr];
            float4 bv4 = *(const float4*)&Bs[k][tc];
            float av[4] = {av4.x, av4.y, av4.z, av4.w};
            float bv[4] = {bv4.x, bv4.y, bv4.z, bv4.w};
            #pragma unroll
            for (int i = 0; i < 4; ++i)
                #pragma unroll
                for (int j = 0; j < 4; ++j)
                    acc[i][j] += av[i] * bv[j];
        }
    }
    #pragma unroll
    for (int i = 0; i < 4; ++i) {
        float4 o;
        o.x = acc[i][0]; o.y = acc[i][1]; o.z = acc[i][2]; o.w = acc[i][3];
        *(float4*)(C + (size_t)(bm + tr + i) * N + bn + tc) = o;
    }
}

// Variant: writes bf16 hi + lo planes (for K).
__global__ __launch_bounds__(256)
void gemm_bt_hilo(const float* __restrict__ A, const float* __restrict__ W,
                  unsigned short* __restrict__ Chi, unsigned short* __restrict__ Clo,
                  int M, int N, int K) {
    __shared__ float As[GKT][GT];
    __shared__ float Bs[GKT][GT];
    const int tid = threadIdx.x;
    const int bm  = blockIdx.y * GT;
    const int bn  = blockIdx.x * GT;
    const int tr = (tid >> 4) << 2;
    const int tc = (tid & 15) << 2;
    const int lr = tid >> 2;
    const int lk = (tid & 3) << 2;
    float acc[4][4] = {{0.f,0.f,0.f,0.f},{0.f,0.f,0.f,0.f},
                       {0.f,0.f,0.f,0.f},{0.f,0.f,0.f,0.f}};
    const float* Arow = A + (size_t)(bm + lr) * K + lk;
    const float* Wrow = W + (size_t)(bn + lr) * K + lk;
    for (int k0 = 0; k0 < K; k0 += GKT) {
        float4 a4 = *(const float4*)(Arow + k0);
        float4 b4 = *(const float4*)(Wrow + k0);
        __syncthreads();
        As[lk + 0][lr] = a4.x; As[lk + 1][lr] = a4.y;
        As[lk + 2][lr] = a4.z; As[lk + 3][lr] = a4.w;
        Bs[lk + 0][lr] = b4.x; Bs[lk + 1][lr] = b4.y;
        Bs[lk + 2][lr] = b4.z; Bs[lk + 3][lr] = b4.w;
        __syncthreads();
        #pragma unroll
        for (int k = 0; k < GKT; ++k) {
            float4 av4 = *(const float4*)&As[k][tr];
            float4 bv4 = *(const float4*)&Bs[k][tc];
            float av[4] = {av4.x, av4.y, av4.z, av4.w};
            float bv[4] = {bv4.x, bv4.y, bv4.z, bv4.w};
            #pragma unroll
            for (int i = 0; i < 4; ++i)
                #pragma unroll
                for (int j = 0; j < 4; ++j)
                    acc[i][j] += av[i] * bv[j];
        }
    }
    #pragma unroll
    for (int i = 0; i < 4; ++i) {
        ushort4 h4, l4;
        float v0 = acc[i][0], v1 = acc[i][1], v2 = acc[i][2], v3 = acc[i][3];
        unsigned short hb;
        hb = bf16_rne(v0); h4.x = hb; l4.x = bf16_rne(v0 - bf16_to_f(hb));
        hb = bf16_rne(v1); h4.y = hb; l4.y = bf16_rne(v1 - bf16_to_f(hb));
        hb = bf16_rne(v2); h4.z = hb; l4.z = bf16_rne(v2 - bf16_to_f(hb));
        hb = bf16_rne(v3); h4.w = hb; l4.w = bf16_rne(v3 - bf16_to_f(hb));
        *(ushort4*)(Chi + (size_t)(bm + tr + i) * N + bn + tc) = h4;
        *(ushort4*)(Clo + (size_t)(bm + tr + i) * N + bn + tc) = l4;
    }
}

// Variant: writes transposed bf16 Vt[b*D_ + dglobal][tloc] (for V).
__global__ __launch_bounds__(256)
void gemm_bt_vt(const float* __restrict__ A, const float* __restrict__ W,
                unsigned short* __restrict__ Vt, int M, int N, int K) {
    __shared__ float As[GKT][GT];
    __shared__ float Bs[GKT][GT];
    const int tid = threadIdx.x;
    const int bm  = blockIdx.y * GT;
    const int bn  = blockIdx.x * GT;
    const int tr = (tid >> 4) << 2;
    const int tc = (tid & 15) << 2;
    const int lr = tid >> 2;
    const int lk = (tid & 3) << 2;
    float acc[4][4] = {{0.f,0.f,0.f,0.f},{0.f,0.f,0.f,0.f},
                       {0.f,0.f,0.f,0.f},{0.f,0.f,0.f,0.f}};
    const float* Arow = A + (size_t)(bm + lr) * K + lk;
    const float* Wrow = W + (size_t)(bn + lr) * K + lk;
    for (int k0 = 0; k0 < K; k0 += GKT) {
        float4 a4 = *(const float4*)(Arow + k0);
        float4 b4 = *(const float4*)(Wrow + k0);
        __syncthreads();
        As[lk + 0][lr] = a4.x; As[lk + 1][lr] = a4.y;
        As[lk + 2][lr] = a4.z; As[lk + 3][lr] = a4.w;
        Bs[lk + 0][lr] = b4.x; Bs[lk + 1][lr] = b4.y;
        Bs[lk + 2][lr] = b4.z; Bs[lk + 3][lr] = b4.w;
        __syncthreads();
        #pragma unroll
        for (int k = 0; k < GKT; ++k) {
            float4 av4 = *(const float4*)&As[k][tr];
            float4 bv4 = *(const float4*)&Bs[k][tc];
            float av[4] = {av4.x, av4.y, av4.z, av4.w};
            float bv[4] = {bv4.x, bv4.y, bv4.z, bv4.w};
            #pragma unroll
            for (int i = 0; i < 4; ++i)
                #pragma unroll
                for (int j = 0; j < 4; ++j)
                    acc[i][j] += av[i] * bv[j];
        }
    }
    const int bD   = bm & ~2047;          // b * D_
    const int tloc = (bm & 2047) + tr;    // key within batch
    #pragma unroll
    for (int j = 0; j < 4; ++j) {
        ushort4 o;
        o.x = bf16_rne(acc[0][j]); o.y = bf16_rne(acc[1][j]);
        o.z = bf16_rne(acc[2][j]); o.w = bf16_rne(acc[3][j]);
        *(ushort4*)(Vt + (size_t)(bD + bn + tc + j) * T_ + tloc) = o;
    }
}

// ---------------------------------------------------------------------------
// Flash-style differential attention with MFMA.
// Per block: 64 q-rows (4 waves x 16), iterate 64-key tiles.
// Swapped QK^T (A=K, B=Q), split-bf16 hi/lo for exact scores.
// LDS XOR-swizzled (granule ^ (row&7)), linear writes from pre-swizzled
// global source addresses. O1/O2 accumulated online, combined at the end.
// ---------------------------------------------------------------------------
__device__ __forceinline__ void softmax_update(f32x4 s[4], f32x4 O[8],
                                               float& m, float& l,
                                               unsigned pk[4][2], int g) {
    float tmax = -1e30f;
    #pragma unroll
    for (int mt = 0; mt < 4; ++mt)
        #pragma unroll
        for (int r = 0; r < 4; ++r) tmax = fmaxf(tmax, s[mt][r]);
    tmax = fmaxf(tmax, __shfl_xor(tmax, 16));
    tmax = fmaxf(tmax, __shfl_xor(tmax, 32));
    float mnew = fmaxf(m, tmax);
    float tsum = 0.f;
    #pragma unroll
    for (int mt = 0; mt < 4; ++mt)
        #pragma unroll
        for (int r = 0; r < 4; ++r) {
            float p = __expf(s[mt][r] - mnew);
            s[mt][r] = p; tsum += p;
        }
    tsum += __shfl_xor(tsum, 16);
    tsum += __shfl_xor(tsum, 32);
    float al = __expf(m - mnew);
    l = l * al + tsum; m = mnew;
    #pragma unroll
    for (int r = 0; r < 4; ++r) {
        float alr = __shfl(al, (g << 2) | r);
        #pragma unroll
        for (int nt = 0; nt < 8; ++nt) O[nt][r] *= alr;
    }
    #pragma unroll
    for (int mt = 0; mt < 4; ++mt) {
        pk[mt][0] = (unsigned)bf16_rne(s[mt][0]) | ((unsigned)bf16_rne(s[mt][1]) << 16);
        pk[mt][1] = (unsigned)bf16_rne(s[mt][2]) | ((unsigned)bf16_rne(s[mt][3]) << 16);
    }
}

__global__ __launch_bounds__(256, 2)
void diff_attn_mfma(const float* Qbuf,
                    const unsigned short* __restrict__ Khi,
                    const unsigned short* __restrict__ Klo,
                    const unsigned short* __restrict__ Vt,
                    const float* __restrict__ lambda_param,
                    float* Out) {
    __shared__ unsigned short khi_s[64 * 128];
    __shared__ unsigned short klo_s[64 * 128];
    __shared__ unsigned short vt_s[128 * 64];

    const int tid  = threadIdx.x;
    const int lane = tid & 63;
    const int w    = tid >> 6;
    const int b    = blockIdx.z, h = blockIdx.y;
    const int t0   = blockIdx.x * 64;
    const int c    = lane & 15;
    const int g    = lane >> 4;

    const float lam = 1.f / (1.f + __expf(-lambda_param[h]));

    // ---- Q fragments (hi/lo), scaled by 1/8 (fold in 1/sqrt(64))
    const int q0 = t0 + w * 16;
    const float* Qg = Qbuf + (size_t)(b * T_ + q0 + c) * D_ + h * DH;
    s16x8 qhi[4], qlo[4];
    #pragma unroll
    for (int kb = 0; kb < 4; ++kb) {
        float v[8];
        float4 f0 = *(const float4*)(Qg + kb * 32 + g * 8);
        float4 f1 = *(const float4*)(Qg + kb * 32 + g * 8 + 4);
        v[0] = f0.x; v[1] = f0.y; v[2] = f0.z; v[3] = f0.w;
        v[4] = f1.x; v[5] = f1.y; v[6] = f1.z; v[7] = f1.w;
        #pragma unroll
        for (int j = 0; j < 8; ++j) {
            float s = v[j] * 0.125f;
            unsigned short hb = bf16_rne(s);
            qhi[kb][j] = (short)hb;
            qlo[kb][j] = (short)bf16_rne(s - bf16_to_f(hb));
        }
    }

    f32x4 O1[8], O2[8];
    #pragma unroll
    for (int nt = 0; nt < 8; ++nt)
        #pragma unroll
        for (int r = 0; r < 4; ++r) { O1[nt][r] = 0.f; O2[nt][r] = 0.f; }
    float m1 = -1e30f, l1 = 0.f, m2 = -1e30f, l2 = 0.f;

    for (int s0 = 0; s0 < T_; s0 += 64) {
        __syncthreads();
        // ---- stage K hi/lo (swizzled source -> linear LDS)
        {
            const size_t rowK = (size_t)(b * T_ + s0);
            #pragma unroll
            for (int i = 0; i < 4; ++i) {
                int key  = i * 16 + (tid >> 4);
                int gsrc = (tid & 15) ^ ((tid >> 4) & 7);
                const size_t goff = (rowK + key) * (size_t)D_ + h * DH + gsrc * 8;
                *(uint4*)&khi_s[(size_t)(i * 256 + tid) * 8] = *(const uint4*)&Khi[goff];
                *(uint4*)&klo_s[(size_t)(i * 256 + tid) * 8] = *(const uint4*)&Klo[goff];
            }
            const size_t rowV = (size_t)(b * D_ + h * DH);
            #pragma unroll
            for (int i = 0; i < 4; ++i) {
                int d    = i * 32 + (tid >> 3);
                int gsrc = (tid & 7) ^ ((tid >> 3) & 7);
                *(uint4*)&vt_s[(size_t)(i * 256 + tid) * 8] =
                    *(const uint4*)&Vt[(rowV + d) * (size_t)T_ + s0 + gsrc * 8];
            }
        }
        __syncthreads();

        // ---- QK^T (S^T tiles), split bf16: hi*hi + hi*lo + lo*hi
        f32x4 s1[4], s2[4];
        #pragma unroll
        for (int mt = 0; mt < 4; ++mt)
            #pragma unroll
            for (int r = 0; r < 4; ++r) { s1[mt][r] = 0.f; s2[mt][r] = 0.f; }
        #pragma unroll
        for (int mt = 0; mt < 4; ++mt) {
            const int key  = mt * 16 + c;
            const int krow = key * 128;
            #pragma unroll
            for (int kb = 0; kb < 4; ++kb) {
                int gp = ((4 * kb + g) ^ (key & 7)) * 8;
                s16x8 ahi = *(const s16x8*)&khi_s[krow + gp];
                s16x8 alo = *(const s16x8*)&klo_s[krow + gp];
                f32x4* acc = (kb < 2) ? &s1[mt] : &s2[mt];
                *acc = __builtin_amdgcn_mfma_f32_16x16x32_bf16(ahi, qhi[kb], *acc, 0, 0, 0);
                *acc = __builtin_amdgcn_mfma_f32_16x16x32_bf16(ahi, qlo[kb], *acc, 0, 0, 0);
                *acc = __builtin_amdgcn_mfma_f32_16x16x32_bf16(alo, qhi[kb], *acc, 0, 0, 0);
            }
        }

        // ---- online softmax both paths; s arrays become P, pk = packed bf16
        unsigned pk1[4][2], pk2[4][2];
        softmax_update(s1, O1, m1, l1, pk1, g);
        softmax_update(s2, O2, m2, l2, pk2, g);

        // ---- PV: A = P (shuffled to A-layout), B = V fragments
        const int srcA = ((2 * (g & 1)) << 4) | c;
        const int srcB = ((2 * (g & 1) + 1) << 4) | c;
        const bool hiSel = (g & 2) != 0;
        #pragma unroll
        for (int kb = 0; kb < 2; ++kb) {
            s16x8 vf[8];
            #pragma unroll
            for (int nt = 0; nt < 8; ++nt) {
                int d  = nt * 16 + c;
                int gp = ((4 * kb + g) ^ (d & 7)) * 8;
                vf[nt] = *(const s16x8*)&vt_s[d * 64 + gp];
            }
            // path 1 A-frag
            unsigned u00 = (unsigned)__shfl((int)pk1[2 * kb][0], srcA);
            unsigned u10 = (unsigned)__shfl((int)pk1[2 * kb + 1][0], srcA);
            unsigned u01 = (unsigned)__shfl((int)pk1[2 * kb][1], srcA);
            unsigned u11 = (unsigned)__shfl((int)pk1[2 * kb + 1][1], srcA);
            unsigned u02 = (unsigned)__shfl((int)pk1[2 * kb][0], srcB);
            unsigned u12 = (unsigned)__shfl((int)pk1[2 * kb + 1][0], srcB);
            unsigned u03 = (unsigned)__shfl((int)pk1[2 * kb][1], srcB);
            unsigned u13 = (unsigned)__shfl((int)pk1[2 * kb + 1][1], srcB);
            union { unsigned u[4]; s16x8 v; } pa1;
            pa1.u[0] = hiSel ? u10 : u00;
            pa1.u[1] = hiSel ? u11 : u01;
            pa1.u[2] = hiSel ? u12 : u02;
            pa1.u[3] = hiSel ? u13 : u03;
            // path 2 A-frag
            unsigned w00 = (unsigned)__shfl((int)pk2[2 * kb][0], srcA);
            unsigned w10 = (unsigned)__shfl((int)pk2[2 * kb + 1][0], srcA);
            unsigned w01 = (unsigned)__shfl((int)pk2[2 * kb][1], srcA);
            unsigned w11 = (unsigned)__shfl((int)pk2[2 * kb + 1][1], srcA);
            unsigned w02 = (unsigned)__shfl((int)pk2[2 * kb][0], srcB);
            unsigned w12 = (unsigned)__shfl((int)pk2[2 * kb + 1][0], srcB);
            unsigned w03 = (unsigned)__shfl((int)pk2[2 * kb][1], srcB);
            unsigned w13 = (unsigned)__shfl((int)pk2[2 * kb + 1][1], srcB);
            union { unsigned u[4]; s16x8 v; } pa2;
            pa2.u[0] = hiSel ? w10 : w00;
            pa2.u[1] = hiSel ? w11 : w01;
            pa2.u[2] = hiSel ? w12 : w02;
            pa2.u[3] = hiSel ? w13 : w03;
            #pragma unroll
            for (int nt = 0; nt < 8; ++nt) {
                O1[nt] = __builtin_amdgcn_mfma_f32_16x16x32_bf16(pa1.v, vf[nt], O1[nt], 0, 0, 0);
                O2[nt] = __builtin_amdgcn_mfma_f32_16x16x32_bf16(pa2.v, vf[nt], O2[nt], 0, 0, 0);
            }
        }
    }

    // ---- epilogue: combine paths, write fp32 O (may alias Q slice of this block)
    float il1[4], il2[4];
    #pragma unroll
    for (int r = 0; r < 4; ++r) {
        float L1 = __shfl(l1, (g << 2) | r);
        float L2 = __shfl(l2, (g << 2) | r);
        il1[r] = 1.f / L1;
        il2[r] = lam / L2;
    }
    float* Og = Out + (size_t)(b * T_ + q0) * D_ + h * DH;
    #pragma unroll
    for (int nt = 0; nt < 8; ++nt)
        #pragma unroll
        for (int r = 0; r < 4; ++r)
            Og[(size_t)(g * 4 + r) * D_ + nt * 16 + c] =
                O1[nt][r] * il1[r] - O2[nt][r] * il2[r];
}

// ---------------------------------------------------------------------------
extern "C" void kernel_launch(void* const* d_in, const int* in_sizes, int n_in,
                              void* d_out, int out_size, void* d_ws, size_t ws_size,
                              hipStream_t stream) {
    const float* x    = (const float*)d_in[0];
    const float* W_q  = (const float*)d_in[1];
    const float* W_k  = (const float*)d_in[2];
    const float* W_v  = (const float*)d_in[3];
    const float* W_o  = (const float*)d_in[4];
    const float* lamp = (const float*)d_in[5];
    float* out = (float*)d_out;

    float*          Qbuf = (float*)d_ws;                                   // 32 MB fp32
    unsigned short* Khi  = (unsigned short*)((char*)d_ws + ((size_t)32 << 20));
    unsigned short* Klo  = Khi + (size_t)BT * D_;                          // 16 MB
    unsigned short* Vt   = Klo + (size_t)BT * D_;                          // 16 MB

    dim3 gg(D_ / GT, BT / GT);                       // (32, 64)
    gemm_bt   <<<gg, 256, 0, stream>>>(x, W_q, Qbuf, BT, D_, D_);
    gemm_bt_hilo<<<gg, 256, 0, stream>>>(x, W_k, Khi, Klo, BT, D_, D_);
    gemm_bt_vt  <<<gg, 256, 0, stream>>>(x, W_v, Vt, BT, D_, D_);

    dim3 ga(T_ / 64, H_, B_);                        // (32, 16, 2)
    diff_attn_mfma<<<ga, 256, 0, stream>>>(Qbuf, Khi, Klo, Vt, lamp, Qbuf /*Out aliases Q*/);

    gemm_bt<<<gg, 256, 0, stream>>>(Qbuf, W_o, out, BT, D_, D_);
}

// Round 3
// 839.278 us; speedup vs baseline: 8.3381x; 2.6024x over previous
//
#include <hip/hip_runtime.h>
#include <math.h>

#define B_  2
#define T_  2048
#define D_  2048
#define H_  16
#define DH  128
#define BT  (B_ * T_)          // 4096 rows

typedef float  f32x4 __attribute__((ext_vector_type(4)));
typedef short  s16x8 __attribute__((ext_vector_type(8)));

__device__ __forceinline__ unsigned short bf16_rne(float f) {
    union { float f; unsigned u; } c; c.f = f;
    unsigned r = c.u + 0x7fffu + ((c.u >> 16) & 1u);
    return (unsigned short)(r >> 16);
}
__device__ __forceinline__ float bf16_to_f(unsigned short h) {
    union { unsigned u; float f; } c; c.u = ((unsigned)h) << 16; return c.f;
}

// Fast split for the GEMM staging hot path: hi = trunc-bf16, lo = halfup-bf16(rem).
// Split-product error ~2^-14 rel -> GEMM error ~1e-4 abs, well under threshold.
__device__ __forceinline__ void split8_fast(const float4& a, const float4& b,
                                            uint4& h, uint4& l) {
    float v[8] = {a.x, a.y, a.z, a.w, b.x, b.y, b.z, b.w};
    unsigned hu[8], lu[8];
    #pragma unroll
    for (int j = 0; j < 8; ++j) {
        union { float f; unsigned u; } cv; cv.f = v[j];
        unsigned hb = cv.u & 0xFFFF0000u;
        union { float f; unsigned u; } cr; cr.f = v[j] - __uint_as_float(hb);
        hu[j] = hb >> 16;
        lu[j] = (cr.u + 0x8000u) >> 16;
    }
    h = make_uint4(hu[0] | (hu[1] << 16), hu[2] | (hu[3] << 16),
                   hu[4] | (hu[5] << 16), hu[6] | (hu[7] << 16));
    l = make_uint4(lu[0] | (lu[1] << 16), lu[2] | (lu[3] << 16),
                   lu[4] | (lu[5] << 16), lu[6] | (lu[7] << 16));
}

// Precompute split (RNE both) — not hot.
__global__ __launch_bounds__(256)
void split_planes(const float* __restrict__ in, unsigned short* __restrict__ hi,
                  unsigned short* __restrict__ lo, size_t n) {
    size_t i = ((size_t)blockIdx.x * 256 + threadIdx.x) * 8;
    if (i >= n) return;
    float4 a = *(const float4*)(in + i);
    float4 b = *(const float4*)(in + i + 4);
    float v[8] = {a.x, a.y, a.z, a.w, b.x, b.y, b.z, b.w};
    unsigned hu[8], lu[8];
    #pragma unroll
    for (int j = 0; j < 8; ++j) {
        unsigned short hb = bf16_rne(v[j]);
        hu[j] = hb;
        lu[j] = bf16_rne(v[j] - bf16_to_f(hb));
    }
    *(uint4*)&hi[i] = make_uint4(hu[0] | (hu[1] << 16), hu[2] | (hu[3] << 16),
                                 hu[4] | (hu[5] << 16), hu[6] | (hu[7] << 16));
    *(uint4*)&lo[i] = make_uint4(lu[0] | (lu[1] << 16), lu[2] | (lu[3] << 16),
                                 lu[4] | (lu[5] << 16), lu[6] | (lu[7] << 16));
}

// ---------------------------------------------------------------------------
// Split-bf16 MFMA GEMM: C = A @ W^T. A: M x K fp32 (or hi/lo planes if APL),
// W: N x K fp32. 128x128 tile, BK=64, 4 waves (2x2), 3-term MFMA.
// EPI: 0 = fp32 C, 1 = hi/lo bf16 planes, 2 = transposed bf16 Vt[(b*D+n)*T+t].
// LDS: XOR-swizzled granules (phys = g ^ (row&7)); staging writes are
// tid-linear (conflict-free) with pre-permuted global source granules.
// ---------------------------------------------------------------------------
#define BM  128
#define BN  128
#define BKK 64

template<int EPI, bool APL>
__global__ __launch_bounds__(256, 2)
void gemm_mfma(const float* __restrict__ Af,
               const unsigned short* __restrict__ Ahg,
               const unsigned short* __restrict__ Alg,
               const float* __restrict__ Wf,
               float* __restrict__ Cf,
               unsigned short* __restrict__ Chi,
               unsigned short* __restrict__ Clo,
               unsigned short* __restrict__ Vt,
               int M, int N, int K) {
    __shared__ unsigned short Ah[BM * BKK];
    __shared__ unsigned short Al[BM * BKK];
    __shared__ unsigned short Bh[BM * BKK];
    __shared__ unsigned short Bl[BM * BKK];

    const int tid  = threadIdx.x;
    const int lane = tid & 63;
    const int w    = tid >> 6;
    const int wr   = w >> 1, wc = w & 1;
    const int c    = lane & 15, g = lane >> 4;

    // XCD-aware swizzle (grid % 8 == 0), consecutive swz share bm (A-panel L2 reuse)
    const int nwg = gridDim.x;
    const int bid = blockIdx.x;
    const int swz = (bid & 7) * (nwg >> 3) + (bid >> 3);
    const int nb  = N / BN;
    const int bm  = (swz / nb) * BM;
    const int bn  = (swz % nb) * BN;

    // staging geometry: granule id n = i*256 + tid -> row = n>>3, lds = n*16B
    const int srow = tid >> 3;                       // 0..31 (+ i*32)
    const int sgs  = (tid & 7) ^ (srow & 7);         // pre-permuted source granule
    const float*          Abase = APL ? nullptr : Af + (size_t)(bm + srow) * K + sgs * 8;
    const unsigned short* Ahb   = APL ? Ahg + (size_t)(bm + srow) * K + sgs * 8 : nullptr;
    const unsigned short* Alb   = APL ? Alg + (size_t)(bm + srow) * K + sgs * 8 : nullptr;
    const float*          Wbase = Wf + (size_t)(bn + srow) * K + sgs * 8;

    float4 ra[8]; uint4 rah[4], ral[4]; float4 rb[8];

    auto LOAD = [&](int k0) {
        #pragma unroll
        for (int i = 0; i < 4; ++i) {
            const size_t o = (size_t)i * 32 * K + k0;
            if constexpr (!APL) {
                ra[2*i]   = *(const float4*)(Abase + o);
                ra[2*i+1] = *(const float4*)(Abase + o + 4);
            } else {
                rah[i] = *(const uint4*)(Ahb + o);
                ral[i] = *(const uint4*)(Alb + o);
            }
            rb[2*i]   = *(const float4*)(Wbase + o);
            rb[2*i+1] = *(const float4*)(Wbase + o + 4);
        }
    };
    auto WRITE = [&]() {
        #pragma unroll
        for (int i = 0; i < 4; ++i) {
            const int ds = (i * 256 + tid) * 8;
            if constexpr (!APL) {
                uint4 h, l; split8_fast(ra[2*i], ra[2*i+1], h, l);
                *(uint4*)&Ah[ds] = h; *(uint4*)&Al[ds] = l;
            } else {
                *(uint4*)&Ah[ds] = rah[i]; *(uint4*)&Al[ds] = ral[i];
            }
            uint4 h, l; split8_fast(rb[2*i], rb[2*i+1], h, l);
            *(uint4*)&Bh[ds] = h; *(uint4*)&Bl[ds] = l;
        }
    };

    f32x4 acc[4][4];
    #pragma unroll
    for (int mi = 0; mi < 4; ++mi)
        #pragma unroll
        for (int ni = 0; ni < 4; ++ni)
            #pragma unroll
            for (int r = 0; r < 4; ++r) acc[mi][ni][r] = 0.f;

    LOAD(0);
    for (int k0 = 0; k0 < K; k0 += BKK) {
        __syncthreads();                 // prev tile consumed
        WRITE();
        __syncthreads();                 // tile ready
        if (k0 + BKK < K) LOAD(k0 + BKK);   // prefetch overlaps MFMA

        #pragma unroll
        for (int kc = 0; kc < 2; ++kc) {
            s16x8 fah[4], fal[4], fbh[4], fbl[4];
            #pragma unroll
            for (int mi = 0; mi < 4; ++mi) {
                const int row = wr * 64 + mi * 16 + c;
                const int off = row * 64 + (((kc * 4 + g) ^ (c & 7)) * 8);
                fah[mi] = *(const s16x8*)&Ah[off];
                fal[mi] = *(const s16x8*)&Al[off];
            }
            #pragma unroll
            for (int ni = 0; ni < 4; ++ni) {
                const int row = wc * 64 + ni * 16 + c;
                const int off = row * 64 + (((kc * 4 + g) ^ (c & 7)) * 8);
                fbh[ni] = *(const s16x8*)&Bh[off];
                fbl[ni] = *(const s16x8*)&Bl[off];
            }
            #pragma unroll
            for (int mi = 0; mi < 4; ++mi)
                #pragma unroll
                for (int ni = 0; ni < 4; ++ni) {
                    acc[mi][ni] = __builtin_amdgcn_mfma_f32_16x16x32_bf16(fah[mi], fbh[ni], acc[mi][ni], 0, 0, 0);
                    acc[mi][ni] = __builtin_amdgcn_mfma_f32_16x16x32_bf16(fah[mi], fbl[ni], acc[mi][ni], 0, 0, 0);
                    acc[mi][ni] = __builtin_amdgcn_mfma_f32_16x16x32_bf16(fal[mi], fbh[ni], acc[mi][ni], 0, 0, 0);
                }
        }
    }

    // epilogue: D[m = (lane>>4)*4+r (first op = A rows)][n = lane&15 (second op = W rows)]
    #pragma unroll
    for (int mi = 0; mi < 4; ++mi) {
        #pragma unroll
        for (int ni = 0; ni < 4; ++ni) {
            const int m0 = bm + wr * 64 + mi * 16 + g * 4;
            const int n  = bn + wc * 64 + ni * 16 + c;
            if constexpr (EPI == 0) {
                #pragma unroll
                for (int r = 0; r < 4; ++r)
                    Cf[(size_t)(m0 + r) * N + n] = acc[mi][ni][r];
            } else if constexpr (EPI == 1) {
                #pragma unroll
                for (int r = 0; r < 4; ++r) {
                    float v = acc[mi][ni][r];
                    unsigned short hb = bf16_rne(v);
                    unsigned short lb = bf16_rne(v - bf16_to_f(hb));
                    Chi[(size_t)(m0 + r) * N + n] = hb;
                    Clo[(size_t)(m0 + r) * N + n] = lb;
                }
            } else {
                const int bb = m0 >> 11, t = m0 & (T_ - 1);
                ushort4 o;
                o.x = bf16_rne(acc[mi][ni][0]); o.y = bf16_rne(acc[mi][ni][1]);
                o.z = bf16_rne(acc[mi][ni][2]); o.w = bf16_rne(acc[mi][ni][3]);
                *(ushort4*)&Vt[((size_t)bb * D_ + n) * T_ + t] = o;
            }
        }
    }
}

// ---------------------------------------------------------------------------
// Flash-style differential attention (unchanged math from round 2), but:
// Q consumed directly from hi/lo planes; scores scaled 0.125 post-MFMA;
// output written as hi/lo planes aliasing the Q planes (block-exclusive slice).
// ---------------------------------------------------------------------------
__device__ __forceinline__ void softmax_update(f32x4 s[4], f32x4 O[8],
                                               float& m, float& l,
                                               unsigned pk[4][2], int g) {
    float tmax = -1e30f;
    #pragma unroll
    for (int mt = 0; mt < 4; ++mt)
        #pragma unroll
        for (int r = 0; r < 4; ++r) {
            s[mt][r] *= 0.125f;          // 1/sqrt(64)
            tmax = fmaxf(tmax, s[mt][r]);
        }
    tmax = fmaxf(tmax, __shfl_xor(tmax, 16));
    tmax = fmaxf(tmax, __shfl_xor(tmax, 32));
    float mnew = fmaxf(m, tmax);
    float tsum = 0.f;
    #pragma unroll
    for (int mt = 0; mt < 4; ++mt)
        #pragma unroll
        for (int r = 0; r < 4; ++r) {
            float p = __expf(s[mt][r] - mnew);
            s[mt][r] = p; tsum += p;
        }
    tsum += __shfl_xor(tsum, 16);
    tsum += __shfl_xor(tsum, 32);
    float al = __expf(m - mnew);
    l = l * al + tsum; m = mnew;
    #pragma unroll
    for (int r = 0; r < 4; ++r) {
        float alr = __shfl(al, (g << 2) | r);
        #pragma unroll
        for (int nt = 0; nt < 8; ++nt) O[nt][r] *= alr;
    }
    #pragma unroll
    for (int mt = 0; mt < 4; ++mt) {
        pk[mt][0] = (unsigned)bf16_rne(s[mt][0]) | ((unsigned)bf16_rne(s[mt][1]) << 16);
        pk[mt][1] = (unsigned)bf16_rne(s[mt][2]) | ((unsigned)bf16_rne(s[mt][3]) << 16);
    }
}

__global__ __launch_bounds__(256, 2)
void diff_attn_mfma(unsigned short* Qhi, unsigned short* Qlo,
                    const unsigned short* __restrict__ Khi,
                    const unsigned short* __restrict__ Klo,
                    const unsigned short* __restrict__ Vt,
                    const float* __restrict__ lambda_param) {
    __shared__ unsigned short khi_s[64 * 128];
    __shared__ unsigned short klo_s[64 * 128];
    __shared__ unsigned short vt_s[128 * 64];

    const int tid  = threadIdx.x;
    const int lane = tid & 63;
    const int w    = tid >> 6;
    const int b    = blockIdx.z, h = blockIdx.y;
    const int t0   = blockIdx.x * 64;
    const int c    = lane & 15;
    const int g    = lane >> 4;

    const float lam = 1.f / (1.f + __expf(-lambda_param[h]));

    // ---- Q fragments straight from planes (unscaled)
    const int q0 = t0 + w * 16;
    const unsigned short* Qhg = Qhi + (size_t)(b * T_ + q0 + c) * D_ + h * DH;
    const unsigned short* Qlg = Qlo + (size_t)(b * T_ + q0 + c) * D_ + h * DH;
    s16x8 qhi[4], qlo[4];
    #pragma unroll
    for (int kb = 0; kb < 4; ++kb) {
        qhi[kb] = *(const s16x8*)&Qhg[kb * 32 + g * 8];
        qlo[kb] = *(const s16x8*)&Qlg[kb * 32 + g * 8];
    }

    f32x4 O1[8], O2[8];
    #pragma unroll
    for (int nt = 0; nt < 8; ++nt)
        #pragma unroll
        for (int r = 0; r < 4; ++r) { O1[nt][r] = 0.f; O2[nt][r] = 0.f; }
    float m1 = -1e30f, l1 = 0.f, m2 = -1e30f, l2 = 0.f;

    for (int s0 = 0; s0 < T_; s0 += 64) {
        __syncthreads();
        // ---- stage K hi/lo + Vt (swizzled source -> linear LDS)
        {
            const size_t rowK = (size_t)(b * T_ + s0);
            #pragma unroll
            for (int i = 0; i < 4; ++i) {
                int key  = i * 16 + (tid >> 4);
                int gsrc = (tid & 15) ^ ((tid >> 4) & 7);
                const size_t goff = (rowK + key) * (size_t)D_ + h * DH + gsrc * 8;
                *(uint4*)&khi_s[(size_t)(i * 256 + tid) * 8] = *(const uint4*)&Khi[goff];
                *(uint4*)&klo_s[(size_t)(i * 256 + tid) * 8] = *(const uint4*)&Klo[goff];
            }
            const size_t rowV = (size_t)(b * D_ + h * DH);
            #pragma unroll
            for (int i = 0; i < 4; ++i) {
                int d    = i * 32 + (tid >> 3);
                int gsrc = (tid & 7) ^ ((tid >> 3) & 7);
                *(uint4*)&vt_s[(size_t)(i * 256 + tid) * 8] =
                    *(const uint4*)&Vt[(rowV + d) * (size_t)T_ + s0 + gsrc * 8];
            }
        }
        __syncthreads();

        // ---- QK^T, split bf16: hi*hi + hi*lo + lo*hi
        f32x4 s1[4], s2[4];
        #pragma unroll
        for (int mt = 0; mt < 4; ++mt)
            #pragma unroll
            for (int r = 0; r < 4; ++r) { s1[mt][r] = 0.f; s2[mt][r] = 0.f; }
        #pragma unroll
        for (int mt = 0; mt < 4; ++mt) {
            const int key  = mt * 16 + c;
            const int krow = key * 128;
            #pragma unroll
            for (int kb = 0; kb < 4; ++kb) {
                int gp = ((4 * kb + g) ^ (key & 7)) * 8;
                s16x8 ahi = *(const s16x8*)&khi_s[krow + gp];
                s16x8 alo = *(const s16x8*)&klo_s[krow + gp];
                f32x4* acc = (kb < 2) ? &s1[mt] : &s2[mt];
                *acc = __builtin_amdgcn_mfma_f32_16x16x32_bf16(ahi, qhi[kb], *acc, 0, 0, 0);
                *acc = __builtin_amdgcn_mfma_f32_16x16x32_bf16(ahi, qlo[kb], *acc, 0, 0, 0);
                *acc = __builtin_amdgcn_mfma_f32_16x16x32_bf16(alo, qhi[kb], *acc, 0, 0, 0);
            }
        }

        unsigned pk1[4][2], pk2[4][2];
        softmax_update(s1, O1, m1, l1, pk1, g);
        softmax_update(s2, O2, m2, l2, pk2, g);

        // ---- PV: A = P (shuffled to A-layout), B = V fragments
        const int srcA = ((2 * (g & 1)) << 4) | c;
        const int srcB = ((2 * (g & 1) + 1) << 4) | c;
        const bool hiSel = (g & 2) != 0;
        #pragma unroll
        for (int kb = 0; kb < 2; ++kb) {
            s16x8 vf[8];
            #pragma unroll
            for (int nt = 0; nt < 8; ++nt) {
                int d  = nt * 16 + c;
                int gp = ((4 * kb + g) ^ (d & 7)) * 8;
                vf[nt] = *(const s16x8*)&vt_s[d * 64 + gp];
            }
            unsigned u00 = (unsigned)__shfl((int)pk1[2 * kb][0], srcA);
            unsigned u10 = (unsigned)__shfl((int)pk1[2 * kb + 1][0], srcA);
            unsigned u01 = (unsigned)__shfl((int)pk1[2 * kb][1], srcA);
            unsigned u11 = (unsigned)__shfl((int)pk1[2 * kb + 1][1], srcA);
            unsigned u02 = (unsigned)__shfl((int)pk1[2 * kb][0], srcB);
            unsigned u12 = (unsigned)__shfl((int)pk1[2 * kb + 1][0], srcB);
            unsigned u03 = (unsigned)__shfl((int)pk1[2 * kb][1], srcB);
            unsigned u13 = (unsigned)__shfl((int)pk1[2 * kb + 1][1], srcB);
            union { unsigned u[4]; s16x8 v; } pa1;
            pa1.u[0] = hiSel ? u10 : u00;
            pa1.u[1] = hiSel ? u11 : u01;
            pa1.u[2] = hiSel ? u12 : u02;
            pa1.u[3] = hiSel ? u13 : u03;
            unsigned w00 = (unsigned)__shfl((int)pk2[2 * kb][0], srcA);
            unsigned w10 = (unsigned)__shfl((int)pk2[2 * kb + 1][0], srcA);
            unsigned w01 = (unsigned)__shfl((int)pk2[2 * kb][1], srcA);
            unsigned w11 = (unsigned)__shfl((int)pk2[2 * kb + 1][1], srcA);
            unsigned w02 = (unsigned)__shfl((int)pk2[2 * kb][0], srcB);
            unsigned w12 = (unsigned)__shfl((int)pk2[2 * kb + 1][0], srcB);
            unsigned w03 = (unsigned)__shfl((int)pk2[2 * kb][1], srcB);
            unsigned w13 = (unsigned)__shfl((int)pk2[2 * kb + 1][1], srcB);
            union { unsigned u[4]; s16x8 v; } pa2;
            pa2.u[0] = hiSel ? w10 : w00;
            pa2.u[1] = hiSel ? w11 : w01;
            pa2.u[2] = hiSel ? w12 : w02;
            pa2.u[3] = hiSel ? w13 : w03;
            #pragma unroll
            for (int nt = 0; nt < 8; ++nt) {
                O1[nt] = __builtin_amdgcn_mfma_f32_16x16x32_bf16(pa1.v, vf[nt], O1[nt], 0, 0, 0);
                O2[nt] = __builtin_amdgcn_mfma_f32_16x16x32_bf16(pa2.v, vf[nt], O2[nt], 0, 0, 0);
            }
        }
    }

    // ---- epilogue: combine paths, write hi/lo planes (aliases this block's Q slice)
    float il1[4], il2[4];
    #pragma unroll
    for (int r = 0; r < 4; ++r) {
        float L1 = __shfl(l1, (g << 2) | r);
        float L2 = __shfl(l2, (g << 2) | r);
        il1[r] = 1.f / L1;
        il2[r] = lam / L2;
    }
    const size_t obase = (size_t)(b * T_ + q0) * D_ + h * DH;
    #pragma unroll
    for (int nt = 0; nt < 8; ++nt)
        #pragma unroll
        for (int r = 0; r < 4; ++r) {
            float o = O1[nt][r] * il1[r] - O2[nt][r] * il2[r];
            unsigned short hb = bf16_rne(o);
            unsigned short lb = bf16_rne(o - bf16_to_f(hb));
            size_t off = obase + (size_t)(g * 4 + r) * D_ + nt * 16 + c;
            Qhi[off] = hb;
            Qlo[off] = lb;
        }
}

// ---------------------------------------------------------------------------
extern "C" void kernel_launch(void* const* d_in, const int* in_sizes, int n_in,
                              void* d_out, int out_size, void* d_ws, size_t ws_size,
                              hipStream_t stream) {
    const float* x    = (const float*)d_in[0];
    const float* W_q  = (const float*)d_in[1];
    const float* W_k  = (const float*)d_in[2];
    const float* W_v  = (const float*)d_in[3];
    const float* W_o  = (const float*)d_in[4];
    const float* lamp = (const float*)d_in[5];
    float* out = (float*)d_out;

    const size_t PL = (size_t)BT * D_;               // 8M elems = 16 MB/plane
    unsigned short* Qhi = (unsigned short*)d_ws;
    unsigned short* Qlo = Qhi + PL;
    unsigned short* Khi = Qhi + 2 * PL;
    unsigned short* Klo = Qhi + 3 * PL;
    unsigned short* Vt  = Qhi + 4 * PL;
    unsigned short* Xhi = Qhi + 5 * PL;
    unsigned short* Xlo = Qhi + 6 * PL;
    const bool xpre = ws_size >= 7 * PL * sizeof(unsigned short);  // 112 MB

    dim3 gg(512);  // (M/128)*(N/128) = 32*16
    if (xpre) {
        split_planes<<<4096, 256, 0, stream>>>(x, Xhi, Xlo, PL);
        gemm_mfma<1, true><<<gg, 256, 0, stream>>>(nullptr, Xhi, Xlo, W_q,
                                                   nullptr, Qhi, Qlo, nullptr, BT, D_, D_);
        gemm_mfma<1, true><<<gg, 256, 0, stream>>>(nullptr, Xhi, Xlo, W_k,
                                                   nullptr, Khi, Klo, nullptr, BT, D_, D_);
        gemm_mfma<2, true><<<gg, 256, 0, stream>>>(nullptr, Xhi, Xlo, W_v,
                                                   nullptr, nullptr, nullptr, Vt, BT, D_, D_);
    } else {
        gemm_mfma<1, false><<<gg, 256, 0, stream>>>(x, nullptr, nullptr, W_q,
                                                    nullptr, Qhi, Qlo, nullptr, BT, D_, D_);
        gemm_mfma<1, false><<<gg, 256, 0, stream>>>(x, nullptr, nullptr, W_k,
                                                    nullptr, Khi, Klo, nullptr, BT, D_, D_);
        gemm_mfma<2, false><<<gg, 256, 0, stream>>>(x, nullptr, nullptr, W_v,
                                                    nullptr, nullptr, nullptr, Vt, BT, D_, D_);
    }

    dim3 ga(T_ / 64, H_, B_);                        // (32, 16, 2)
    diff_attn_mfma<<<ga, 256, 0, stream>>>(Qhi, Qlo, Khi, Klo, Vt, lamp);

    gemm_mfma<0, true><<<gg, 256, 0, stream>>>(nullptr, Qhi, Qlo, W_o,
                                               out, nullptr, nullptr, nullptr, BT, D_, D_);
}

// Round 4
// 365.959 us; speedup vs baseline: 19.1224x; 2.2934x over previous
//
#include <hip/hip_runtime.h>
#include <math.h>

#define B_  2
#define T_  2048
#define D_  2048
#define H_  16
#define DH  128
#define BT  (B_ * T_)          // 4096 rows

typedef float    f32x4 __attribute__((ext_vector_type(4)));
typedef _Float16 f16x8 __attribute__((ext_vector_type(8)));

typedef __attribute__((address_space(1))) const void* gas_t;
typedef __attribute__((address_space(3))) void*       las_t;

__device__ __forceinline__ void gll16(const void* g, void* l) {
    __builtin_amdgcn_global_load_lds((gas_t)g, (las_t)l, 16, 0, 0);
}

__device__ __forceinline__ unsigned short h16bits(float f) {
    union { _Float16 h; unsigned short u; } c; c.h = (_Float16)f; return c.u;
}

// ---------------------------------------------------------------------------
// fp32 -> fp16 conversion (prep pass, memory-bound)
// ---------------------------------------------------------------------------
__global__ __launch_bounds__(256)
void f32_to_f16(const float* __restrict__ in, _Float16* __restrict__ out, int n8) {
    int i = blockIdx.x * 256 + threadIdx.x;
    if (i >= n8) return;
    const float4 a = *(const float4*)(in + (size_t)i * 8);
    const float4 b = *(const float4*)(in + (size_t)i * 8 + 4);
    f16x8 o;
    o[0] = (_Float16)a.x; o[1] = (_Float16)a.y; o[2] = (_Float16)a.z; o[3] = (_Float16)a.w;
    o[4] = (_Float16)b.x; o[5] = (_Float16)b.y; o[6] = (_Float16)b.z; o[7] = (_Float16)b.w;
    *(f16x8*)(out + (size_t)i * 8) = o;
}

// ---------------------------------------------------------------------------
// fp16 MFMA GEMM (m97 structure): C = A @ W^T. A,W fp16 planes.
// 128x128 tile, BK=64, 4 waves, global_load_lds(16B) staging, XOR-swizzled
// LDS achieved via pre-permuted global source granules + linear LDS dest.
// EPI: 0 = fp32 C, 1 = fp16 C, 2 = transposed fp16 Vt[(b*D+n)*T + t].
// ---------------------------------------------------------------------------
#define BKK 64

template<int EPI>
__global__ __launch_bounds__(256, 2)
void gemm16(const _Float16* __restrict__ Ag, const _Float16* __restrict__ Bg,
            float* __restrict__ Cf, _Float16* __restrict__ C16,
            _Float16* __restrict__ Vt, int M, int N, int K) {
    __shared__ _Float16 As[128 * BKK];
    __shared__ _Float16 Bs[128 * BKK];

    const int tid  = threadIdx.x;
    const int lane = tid & 63;
    const int w    = tid >> 6;
    const int wr   = w >> 1, wc = w & 1;
    const int c    = lane & 15, g = lane >> 4;

    // XCD-aware swizzle (grid % 8 == 0): consecutive swz share bm (A-panel L2 reuse)
    const int nwg = gridDim.x;
    const int bid = blockIdx.x;
    const int swz = (bid & 7) * (nwg >> 3) + (bid >> 3);
    const int nb  = N / 128;
    const int bm  = (swz / nb) * 128;
    const int bn  = (swz % nb) * 128;

    // staging: granule n = i*256 + tid -> row = n>>3, lds byte = n*16 (lane-linear)
    const int srow = tid >> 3;                       // 0..31 (+ i*32)
    const int sg   = (tid & 7) ^ (srow & 7);         // pre-permuted source granule
    const _Float16* Ab = Ag + (size_t)(bm + srow) * K + sg * 8;
    const _Float16* Bb = Bg + (size_t)(bn + srow) * K + sg * 8;

    f32x4 acc[4][4];
    #pragma unroll
    for (int mi = 0; mi < 4; ++mi)
        #pragma unroll
        for (int ni = 0; ni < 4; ++ni)
            #pragma unroll
            for (int r = 0; r < 4; ++r) acc[mi][ni][r] = 0.f;

    for (int k0 = 0; k0 < K; k0 += BKK) {
        __syncthreads();                 // prev tile consumed
        #pragma unroll
        for (int i = 0; i < 4; ++i) {
            gll16(Ab + (size_t)i * 32 * K + k0, &As[(i * 256 + tid) * 8]);
            gll16(Bb + (size_t)i * 32 * K + k0, &Bs[(i * 256 + tid) * 8]);
        }
        __syncthreads();                 // drains vmcnt: tile ready

        #pragma unroll
        for (int kc = 0; kc < 2; ++kc) {
            f16x8 fa[4], fb[4];
            #pragma unroll
            for (int mi = 0; mi < 4; ++mi) {
                const int row = wr * 64 + mi * 16 + c;
                fa[mi] = *(const f16x8*)&As[row * 64 + (((kc * 4 + g) ^ (c & 7)) * 8)];
            }
            #pragma unroll
            for (int ni = 0; ni < 4; ++ni) {
                const int row = wc * 64 + ni * 16 + c;
                fb[ni] = *(const f16x8*)&Bs[row * 64 + (((kc * 4 + g) ^ (c & 7)) * 8)];
            }
            #pragma unroll
            for (int mi = 0; mi < 4; ++mi)
                #pragma unroll
                for (int ni = 0; ni < 4; ++ni)
                    acc[mi][ni] = __builtin_amdgcn_mfma_f32_16x16x32_f16(fa[mi], fb[ni], acc[mi][ni], 0, 0, 0);
        }
    }

    // epilogue: D[m = g*4+r (A rows)][n = c (W rows)]
    #pragma unroll
    for (int mi = 0; mi < 4; ++mi) {
        #pragma unroll
        for (int ni = 0; ni < 4; ++ni) {
            const int m0 = bm + wr * 64 + mi * 16 + g * 4;
            const int n  = bn + wc * 64 + ni * 16 + c;
            if constexpr (EPI == 0) {
                #pragma unroll
                for (int r = 0; r < 4; ++r)
                    Cf[(size_t)(m0 + r) * N + n] = acc[mi][ni][r];
            } else if constexpr (EPI == 1) {
                #pragma unroll
                for (int r = 0; r < 4; ++r)
                    C16[(size_t)(m0 + r) * N + n] = (_Float16)acc[mi][ni][r];
            } else {
                const int bb = m0 >> 11, t = m0 & (T_ - 1);
                ushort4 o;
                o.x = h16bits(acc[mi][ni][0]); o.y = h16bits(acc[mi][ni][1]);
                o.z = h16bits(acc[mi][ni][2]); o.w = h16bits(acc[mi][ni][3]);
                *(ushort4*)&Vt[((size_t)bb * D_ + n) * T_ + t] = o;
            }
        }
    }
}

// ---------------------------------------------------------------------------
// Flash-style differential attention, all fp16, double-buffered gll staging.
// Per block: 64 q-rows (4 waves x 16), 64-key tiles, swapped QK^T.
// defer-max (THR=8): skip O-rescale unless some q's tile max exceeds m+8.
// ---------------------------------------------------------------------------
__device__ __forceinline__ void softmax_upd(f32x4 s[4], f32x4 O[8],
                                            float& m, float& l,
                                            unsigned pk[4][2], int g) {
    float tmax = -1e30f;
    #pragma unroll
    for (int mt = 0; mt < 4; ++mt)
        #pragma unroll
        for (int r = 0; r < 4; ++r) {
            s[mt][r] *= 0.125f;          // 1/sqrt(64)
            tmax = fmaxf(tmax, s[mt][r]);
        }
    tmax = fmaxf(tmax, __shfl_xor(tmax, 16));
    tmax = fmaxf(tmax, __shfl_xor(tmax, 32));
    if (!__all(tmax <= m + 8.f)) {       // rescale path (rare after warmup)
        float mnew = fmaxf(m, tmax);
        float al   = __expf(m - mnew);
        #pragma unroll
        for (int r = 0; r < 4; ++r) {
            float alr = __shfl(al, (g << 2) | r);
            #pragma unroll
            for (int nt = 0; nt < 8; ++nt) O[nt][r] *= alr;
        }
        l *= al;
        m  = mnew;
    }
    float tsum = 0.f;
    #pragma unroll
    for (int mt = 0; mt < 4; ++mt)
        #pragma unroll
        for (int r = 0; r < 4; ++r) {
            float p = __expf(s[mt][r] - m);   // bounded by e^8
            s[mt][r] = p; tsum += p;
        }
    tsum += __shfl_xor(tsum, 16);
    tsum += __shfl_xor(tsum, 32);
    l += tsum;
    #pragma unroll
    for (int mt = 0; mt < 4; ++mt) {
        pk[mt][0] = (unsigned)h16bits(s[mt][0]) | ((unsigned)h16bits(s[mt][1]) << 16);
        pk[mt][1] = (unsigned)h16bits(s[mt][2]) | ((unsigned)h16bits(s[mt][3]) << 16);
    }
}

__global__ __launch_bounds__(256, 2)
void diff_attn_f16(_Float16* Qh,
                   const _Float16* __restrict__ Kh,
                   const _Float16* __restrict__ Vt,
                   const float* __restrict__ lambda_param) {
    __shared__ _Float16 k_s[2][64 * 128];
    __shared__ _Float16 v_s[2][128 * 64];

    const int tid  = threadIdx.x;
    const int lane = tid & 63;
    const int w    = tid >> 6;
    const int b    = blockIdx.z, h = blockIdx.y;
    const int t0   = blockIdx.x * 64;
    const int c    = lane & 15;
    const int g    = lane >> 4;

    const float lam = 1.f / (1.f + __expf(-lambda_param[h]));

    // ---- Q fragments (fp16 plane, unscaled; 0.125 applied post-MFMA)
    const int q0 = t0 + w * 16;
    const _Float16* Qg = Qh + (size_t)(b * T_ + q0 + c) * D_ + h * DH;
    f16x8 qf[4];
    #pragma unroll
    for (int kb = 0; kb < 4; ++kb)
        qf[kb] = *(const f16x8*)&Qg[kb * 32 + g * 8];

    f32x4 O1[8], O2[8];
    #pragma unroll
    for (int nt = 0; nt < 8; ++nt)
        #pragma unroll
        for (int r = 0; r < 4; ++r) { O1[nt][r] = 0.f; O2[nt][r] = 0.f; }
    float m1 = -1e30f, l1 = 0.f, m2 = -1e30f, l2 = 0.f;

    // staging geometry (all lane-linear LDS dests for gll)
    const int kkey = tid >> 4;                       // + i*16
    const int kgs  = (tid & 15) ^ (kkey & 7);
    const int vd   = tid >> 3;                       // + i*32
    const int vgs  = (tid & 7) ^ (vd & 7);
    const size_t rowK = (size_t)(b * T_);
    const size_t rowV = (size_t)(b * D_ + h * DH);

    auto STAGE = [&](int s0, int buf) {
        #pragma unroll
        for (int i = 0; i < 4; ++i) {
            const size_t goff = (rowK + s0 + i * 16 + kkey) * (size_t)D_ + h * DH + kgs * 8;
            gll16(&Kh[goff], &k_s[buf][(i * 256 + tid) * 8]);
        }
        #pragma unroll
        for (int i = 0; i < 4; ++i) {
            const size_t goff = (rowV + i * 32 + vd) * (size_t)T_ + s0 + vgs * 8;
            gll16(&Vt[goff], &v_s[buf][(i * 256 + tid) * 8]);
        }
    };

    STAGE(0, 0);
    __syncthreads();                                 // drain: tile 0 ready

    const int NT = T_ / 64;
    for (int t = 0; t < NT; ++t) {
        const int cur = t & 1;
        if (t + 1 < NT) STAGE((t + 1) * 64, cur ^ 1);   // in flight during compute

        // ---- QK^T (S^T tiles): A = K (LDS), B = Q (regs)
        f32x4 s1[4], s2[4];
        #pragma unroll
        for (int mt = 0; mt < 4; ++mt)
            #pragma unroll
            for (int r = 0; r < 4; ++r) { s1[mt][r] = 0.f; s2[mt][r] = 0.f; }
        #pragma unroll
        for (int mt = 0; mt < 4; ++mt) {
            const int key  = mt * 16 + c;
            const int krow = key * 128;
            #pragma unroll
            for (int kb = 0; kb < 4; ++kb) {
                const int gp = ((4 * kb + g) ^ (key & 7)) * 8;
                f16x8 kf = *(const f16x8*)&k_s[cur][krow + gp];
                if (kb < 2) s1[mt] = __builtin_amdgcn_mfma_f32_16x16x32_f16(kf, qf[kb], s1[mt], 0, 0, 0);
                else        s2[mt] = __builtin_amdgcn_mfma_f32_16x16x32_f16(kf, qf[kb], s2[mt], 0, 0, 0);
            }
        }

        unsigned pk1[4][2], pk2[4][2];
        softmax_upd(s1, O1, m1, l1, pk1, g);
        softmax_upd(s2, O2, m2, l2, pk2, g);

        // ---- PV: A = P (shuffled to A-layout), B = V fragments
        const int srcA = ((2 * (g & 1)) << 4) | c;
        const int srcB = ((2 * (g & 1) + 1) << 4) | c;
        const bool hiSel = (g & 2) != 0;
        #pragma unroll
        for (int kb = 0; kb < 2; ++kb) {
            f16x8 vf[8];
            #pragma unroll
            for (int nt = 0; nt < 8; ++nt) {
                const int d  = nt * 16 + c;
                const int gp = ((4 * kb + g) ^ (d & 7)) * 8;
                vf[nt] = *(const f16x8*)&v_s[cur][d * 64 + gp];
            }
            unsigned u00 = (unsigned)__shfl((int)pk1[2 * kb][0], srcA);
            unsigned u10 = (unsigned)__shfl((int)pk1[2 * kb + 1][0], srcA);
            unsigned u01 = (unsigned)__shfl((int)pk1[2 * kb][1], srcA);
            unsigned u11 = (unsigned)__shfl((int)pk1[2 * kb + 1][1], srcA);
            unsigned u02 = (unsigned)__shfl((int)pk1[2 * kb][0], srcB);
            unsigned u12 = (unsigned)__shfl((int)pk1[2 * kb + 1][0], srcB);
            unsigned u03 = (unsigned)__shfl((int)pk1[2 * kb][1], srcB);
            unsigned u13 = (unsigned)__shfl((int)pk1[2 * kb + 1][1], srcB);
            union { unsigned u[4]; f16x8 v; } pa1;
            pa1.u[0] = hiSel ? u10 : u00;
            pa1.u[1] = hiSel ? u11 : u01;
            pa1.u[2] = hiSel ? u12 : u02;
            pa1.u[3] = hiSel ? u13 : u03;
            unsigned w00 = (unsigned)__shfl((int)pk2[2 * kb][0], srcA);
            unsigned w10 = (unsigned)__shfl((int)pk2[2 * kb + 1][0], srcA);
            unsigned w01 = (unsigned)__shfl((int)pk2[2 * kb][1], srcA);
            unsigned w11 = (unsigned)__shfl((int)pk2[2 * kb + 1][1], srcA);
            unsigned w02 = (unsigned)__shfl((int)pk2[2 * kb][0], srcB);
            unsigned w12 = (unsigned)__shfl((int)pk2[2 * kb + 1][0], srcB);
            unsigned w03 = (unsigned)__shfl((int)pk2[2 * kb][1], srcB);
            unsigned w13 = (unsigned)__shfl((int)pk2[2 * kb + 1][1], srcB);
            union { unsigned u[4]; f16x8 v; } pa2;
            pa2.u[0] = hiSel ? w10 : w00;
            pa2.u[1] = hiSel ? w11 : w01;
            pa2.u[2] = hiSel ? w12 : w02;
            pa2.u[3] = hiSel ? w13 : w03;
            #pragma unroll
            for (int nt = 0; nt < 8; ++nt) {
                O1[nt] = __builtin_amdgcn_mfma_f32_16x16x32_f16(pa1.v, vf[nt], O1[nt], 0, 0, 0);
                O2[nt] = __builtin_amdgcn_mfma_f32_16x16x32_f16(pa2.v, vf[nt], O2[nt], 0, 0, 0);
            }
        }
        __syncthreads();   // drains vmcnt (next tile landed) + gates buffer reuse
    }

    // ---- epilogue: combine paths, write fp16 (aliases this block's Q slice)
    float il1[4], il2[4];
    #pragma unroll
    for (int r = 0; r < 4; ++r) {
        float L1 = __shfl(l1, (g << 2) | r);
        float L2 = __shfl(l2, (g << 2) | r);
        il1[r] = 1.f / L1;
        il2[r] = lam / L2;
    }
    const size_t obase = (size_t)(b * T_ + q0) * D_ + h * DH;
    #pragma unroll
    for (int nt = 0; nt < 8; ++nt)
        #pragma unroll
        for (int r = 0; r < 4; ++r) {
            float o = O1[nt][r] * il1[r] - O2[nt][r] * il2[r];
            Qh[obase + (size_t)(g * 4 + r) * D_ + nt * 16 + c] = (_Float16)o;
        }
}

// ---------------------------------------------------------------------------
extern "C" void kernel_launch(void* const* d_in, const int* in_sizes, int n_in,
                              void* d_out, int out_size, void* d_ws, size_t ws_size,
                              hipStream_t stream) {
    const float* x    = (const float*)d_in[0];
    const float* W_q  = (const float*)d_in[1];
    const float* W_k  = (const float*)d_in[2];
    const float* W_v  = (const float*)d_in[3];
    const float* W_o  = (const float*)d_in[4];
    const float* lamp = (const float*)d_in[5];
    float* out = (float*)d_out;

    const size_t PL = (size_t)BT * D_;               // 8.4M elems
    const size_t WL = (size_t)D_ * D_;               // 4.2M elems
    _Float16* Xh = (_Float16*)d_ws;                  // 16 MB
    _Float16* Wq = Xh + PL;                          // 8 MB (recycled for W_o)
    _Float16* Wk = Wq + WL;                          // 8 MB
    _Float16* Wv = Wk + WL;                          // 8 MB
    _Float16* Qh = Wv + WL;                          // 16 MB (attn out alias)
    _Float16* Kh = Qh + PL;                          // 16 MB
    _Float16* Vt = Kh + PL;                          // 16 MB  (total 92.3 MB)
    _Float16* Wo = Wq;                               // dead after Q-GEMM

    f32_to_f16<<<(int)(PL / 8 / 256), 256, 0, stream>>>(x,   Xh, (int)(PL / 8));
    f32_to_f16<<<(int)(WL / 8 / 256), 256, 0, stream>>>(W_q, Wq, (int)(WL / 8));
    f32_to_f16<<<(int)(WL / 8 / 256), 256, 0, stream>>>(W_k, Wk, (int)(WL / 8));
    f32_to_f16<<<(int)(WL / 8 / 256), 256, 0, stream>>>(W_v, Wv, (int)(WL / 8));

    dim3 gg(512);  // (M/128)*(N/128) = 32*16
    gemm16<1><<<gg, 256, 0, stream>>>(Xh, Wq, nullptr, Qh, nullptr, BT, D_, D_);
    gemm16<1><<<gg, 256, 0, stream>>>(Xh, Wk, nullptr, Kh, nullptr, BT, D_, D_);
    gemm16<2><<<gg, 256, 0, stream>>>(Xh, Wv, nullptr, nullptr, Vt, BT, D_, D_);

    f32_to_f16<<<(int)(WL / 8 / 256), 256, 0, stream>>>(W_o, Wo, (int)(WL / 8));

    dim3 ga(T_ / 64, H_, B_);                        // (32, 16, 2)
    diff_attn_f16<<<ga, 256, 0, stream>>>(Qh, Kh, Vt, lamp);

    gemm16<0><<<gg, 256, 0, stream>>>(Qh, Wo, out, nullptr, nullptr, BT, D_, D_);
}